// Round 10
// baseline (39.051 us; speedup 1.0000x reference)
//
#include <hip/hip_runtime.h>
#include <math.h>

#define NSEG 2048
#define ROW 65
#define MMAX 4226          // max flat coef entries (M+1), M <= 64*65+64 = 4224
#define TCAP 4240          // flat knot array capacity incl window-read padding
#define NC 4096            // grid cells
#define GLO (-9.0f)
#define GHI (9.0f)
#define DXF ((GHI - GLO) / NC)
#define INVDX (NC / (GHI - GLO))
#define PPT_E 4            // eval: 1954 blocks, ~30 waves/CU
#define CAP 64             // per-block segment-aggregation slots
#define SCALEF 1073741824.0f  // 2^30 (exact exponent shift in fp32)
#define SCALE  1073741824.0

// ---- k_pre_ab: zero accumulators + per-interval crossing tables ----
__global__ __launch_bounds__(64) void k_pre_ab(
    const float* __restrict__ W1, const float* __restrict__ b1,
    const float* __restrict__ W2, const float* __restrict__ b2,
    const float* __restrict__ W3,
    unsigned long long* __restrict__ pooled, int* __restrict__ counts,
    float* __restrict__ bpg, float* __restrict__ knots, float2* __restrict__ coef,
    int* __restrict__ nvalid)
{
    __shared__ float bps[64];
    __shared__ float w2s[64 * 65];   // padded: row stride 65 kills bank conflicts
    __shared__ float sc_[64], sda[64], sdb[64];
    const int lane = threadIdx.x;
    const int k = blockIdx.x;

    // zero the global accumulators (spread across the 65 blocks)
    for (int i = k * 64 + lane; i < NSEG; i += 65 * 64) { pooled[i] = 0ull; counts[i] = 0; }

    // breakpoints: t_j = -b1/W1 (W1==0 -> sentinel), stable shfl rank-sort
    float w1l = W1[lane], b1l = b1[lane];
    float t = (w1l != 0.0f) ? (-b1l / w1l) : 3.0e38f;
    int r = 0;
    for (int l = 0; l < 64; ++l) {
        float o = __shfl(t, l);
        r += (o < t) || (o == t && l < lane);
    }
    bps[r] = t;

    // stage W2 into padded LDS (coalesced global reads)
    for (int i = lane; i < 4096; i += 64)
        w2s[(i >> 6) * 65 + (i & 63)] = W2[i];
    __syncthreads();
    if (k == 0) bpg[lane] = bps[lane];

    // affine coeffs of z_i (i = lane) on interval k: z = a*x + b
    float lof = (k == 0) ? (bps[0] - 1.0f) : bps[k - 1];
    float hif = (k == 64) ? (bps[63] + 1.0f) : bps[k];
    float xm = lof + 0.5f * (hif - lof);
    float a = 0.0f, b = b2[lane];
    for (int j = 0; j < 64; ++j) {
        float w1 = W1[j];
        if (w1 * xm + b1[j] > 0.0f) {
            float w2 = w2s[lane * 65 + j];
            a += w2 * w1;
            b += w2 * b1[j];
        }
    }

    // outer-relu crossing of z_i inside the open interval
    float w3 = W3[lane];
    float lo = (k == 0) ? -INFINITY : bps[k - 1];
    float hi = (k == 64) ? INFINITY : bps[k];
    float c = INFINITY, da = 0.0f, db = 0.0f;
    if (a != 0.0f) {
        float cc = -b / a;
        if (cc > lo && cc < hi) {
            float s = (a > 0.0f) ? 1.0f : -1.0f;
            c = cc; da = s * w3 * a; db = s * w3 * b;
        }
    }
    // active set just right of left edge -> (a0,b0)
    bool act;
    if (k == 0) act = (a < 0.0f) || (a == 0.0f && b > 0.0f);
    else { float v = a * lo + b; act = (v > 0.0f) || (v == 0.0f && a > 0.0f); }
    float a0 = act ? w3 * a : 0.0f;
    float b0 = act ? w3 * b : 0.0f;
    for (int d = 32; d; d >>= 1) { a0 += __shfl_xor(a0, d); b0 += __shfl_xor(b0, d); }

    // stable rank sort of crossings (inf = invalid go last); scatter via LDS
    int rank = 0;
    for (int l = 0; l < 64; ++l) {
        float o = __shfl(c, l);
        rank += (o < c) || (o == c && l < lane);
    }
    sc_[rank] = c; sda[rank] = da; sdb[rank] = db;
    __syncthreads();
    float cs = sc_[lane], das = sda[lane], dbs = sdb[lane];
    for (int d = 1; d < 64; d <<= 1) {  // inclusive scan in sorted order
        float ta = __shfl_up(das, d);
        float tb = __shfl_up(dbs, d);
        if (lane >= d) { das += ta; dbs += tb; }
    }
    knots[k * ROW + lane] = cs;
    if (lane == 0) coef[k * ROW] = make_float2(a0, b0);
    coef[k * ROW + lane + 1] = make_float2(a0 + das, b0 + dbs);

    unsigned long long vm = __ballot(isfinite(cs));
    if (lane == 0) nvalid[k] = (int)__popcll(vm);
}

// ---- k_pre_c2: parallel flatten + per-cell coefficient table ----
// Block k: off[k] via wave scan of nvalid; writes its flat T/C row slice;
// for each grid cell it owns (left edge in [bps[k-1], bps[k])) writes
// cellTab[c] = (a, b, t1, base_bits): (a,b) valid for x in [left, t1),
// t1 = first knot strictly > left, base = #{T <= left} for the fallback.
__global__ __launch_bounds__(64) void k_pre_c2(
    const float* __restrict__ bpg, const int* __restrict__ nvalid,
    const float* __restrict__ knots2d, const float2* __restrict__ coef2d,
    float* __restrict__ Tf, float2* __restrict__ Cf,
    float4* __restrict__ cellTab)
{
    const int lane = threadIdx.x;
    const int k = blockIdx.x;
    __shared__ float bps[64];
    __shared__ float trow[64];

    bps[lane] = bpg[lane];
    trow[lane] = knots2d[k * ROW + lane];   // sorted fine knots, inf past nvalid

    // off[k] = sum_{k'<k} (nvalid[k']+1) via inclusive shfl scan over 64 lanes
    int v = nvalid[lane] + 1;
    int sc = v;
    for (int d = 1; d < 64; d <<= 1) {
        int tt = __shfl_up(sc, d);
        if (lane >= d) sc += tt;
    }
    const int offk  = (k == 0) ? 0 : __shfl(sc, k - 1);
    const int off64 = __shfl(sc, 63);
    const int nv    = nvalid[k];
    __syncthreads();

    // flat row slice: nv fine knots, then coarse bps[k] (k<64); coef j=0..nv
    for (int j = lane; j <= nv; j += 64) {
        if (j < nv) Tf[offk + j] = trow[j];
        else if (k < 64) Tf[offk + j] = bps[k];
        Cf[offk + j] = coef2d[k * ROW + j];
    }
    if (k == 64) {  // sentinels + coef pad beyond M
        const int M = off64 + nvalid[64];
        float2 lastC = coef2d[64 * ROW + nvalid[64]];
        for (int i = M + lane; i < TCAP; i += 64) Tf[i] = INFINITY;
        for (int i = M + 1 + lane; i < MMAX; i += 64) Cf[i] = lastC;
    }

    // grid cells owned by interval k
    float lob = (k == 0) ? GLO : bps[k - 1];
    float hib = (k == 64) ? GHI : bps[k];
    float clo = fminf(fmaxf((lob - GLO) * INVDX, 0.0f), (float)(NC - 1));
    float chi = fminf(fmaxf((hib - GLO) * INVDX, 0.0f), (float)(NC - 1));
    int c0 = max(0, (int)clo - 1);
    int c1 = min(NC - 1, (int)chi + 1);
    for (int c = c0 + lane; c <= c1; c += 64) {
        float left = GLO + c * DXF;
        bool ok = (k == 0 || left >= bps[k - 1]) && (k == 64 || left < bps[k]);
        if (ok) {
            int j = 0;  // #{fine knots <= left}; inf-padding makes 64-search safe
#pragma unroll
            for (int ofs = 32; ofs >= 1; ofs >>= 1)
                if (trow[j + ofs - 1] <= left) j += ofs;
            if (j < 64 && trow[j] <= left) ++j;
            // next knot strictly > left: next fine knot in this interval, or
            // the interval's right edge bps[k] (fine knots are all < bps[k])
            float t1 = (j < 64) ? trow[j] : INFINITY;
            if (k < 64) t1 = fminf(t1, bps[k]);
            float2 ab = coef2d[k * ROW + j];
            cellTab[c] = make_float4(ab.x, ab.y, t1, __int_as_float(offk + j));
        }
    }
}

// ---- k_eval: one-load per-cell lookup + rare fallback + segment pooling ----
__global__ __launch_bounds__(256) void k_eval(
    const float* __restrict__ x, const int* __restrict__ batch,
    const float* __restrict__ Tf, const float2* __restrict__ Cf,
    const float4* __restrict__ cellT,
    unsigned long long* __restrict__ pooled, int* __restrict__ counts,
    int* __restrict__ seg_start, int n)
{
    __shared__ unsigned long long aggP[CAP];
    __shared__ int aggC[CAP];
    __shared__ int segFirst_s;
    const int tid = threadIdx.x;
    if (tid < CAP) { aggP[tid] = 0ull; aggC[tid] = 0; }

    long long base = ((long long)blockIdx.x * 256 + tid) * PPT_E;
    const bool active = base < n;   // n % PPT_E == 0 -> active threads do full vectors

    float xs[PPT_E]; int ss[PPT_E];
    if (active) {
        float4 xv4 = *(const float4*)(x + base);
        int4   s4  = *(const int4*)(batch + base);
        xs[0] = xv4.x; xs[1] = xv4.y; xs[2] = xv4.z; xs[3] = xv4.w;
        ss[0] = s4.x;  ss[1] = s4.y;  ss[2] = s4.z;  ss[3] = s4.w;
        if (tid == 0) segFirst_s = ss[0];
        // segment-boundary detection (sorted batch): first point of each segment
        int prev = (base > 0) ? batch[base - 1] : -1;
        if (ss[0] != prev) seg_start[ss[0]] = (int)base;
#pragma unroll
        for (int p = 1; p < PPT_E; ++p)
            if (ss[p] != ss[p - 1]) seg_start[ss[p]] = (int)(base + p);
    }
    __syncthreads();
    const int segFirst = segFirst_s;

    if (active) {
        int curSeg = -1; long long acc = 0; int cnt = 0;
#pragma unroll
        for (int p = 0; p < PPT_E; ++p) {
            float xv = xs[p];
            float g;
            if (xv >= GLO) {
                int c = (int)((xv - GLO) * INVDX);
                c = c < NC - 1 ? c : NC - 1;
                if (c > 0 && GLO + c * DXF > xv) --c;  // fp rounding guard
                float4 cd = cellT[c];
                if (xv < cd.z) {
                    g = fmaf(cd.x, xv, cd.y);   // clean cell / pre-knot: exact
                } else {
                    // fallback: window count from global flat tables (rare)
                    int b0i = __float_as_int(cd.w);
                    int a0 = b0i & ~3;
                    const float4* tw = (const float4*)(Tf + a0);
                    float4 t0 = tw[0], t1 = tw[1], t2 = tw[2];
                    int cw = (t0.x <= xv) + (t0.y <= xv) + (t0.z <= xv) + (t0.w <= xv)
                           + (t1.x <= xv) + (t1.y <= xv) + (t1.z <= xv) + (t1.w <= xv)
                           + (t2.x <= xv) + (t2.y <= xv) + (t2.z <= xv) + (t2.w <= xv);
                    int m = a0 + cw;
                    if (cw == 12) { while (Tf[m] <= xv) ++m; }
                    float2 ab = Cf[m];
                    g = fmaf(ab.x, xv, ab.y);
                }
            } else {
                float2 ab = Cf[0];
                g = fmaf(ab.x, xv, ab.y);
            }
            long long q = (long long)(g * SCALEF);  // exact: *2^30 is exponent shift
            int s = ss[p];
            if (s != curSeg) {
                if (cnt) {
                    int idx = curSeg - segFirst;
                    if (idx < CAP) {
                        atomicAdd(&aggP[idx], (unsigned long long)acc);
                        atomicAdd(&aggC[idx], cnt);
                    } else {
                        atomicAdd(&pooled[curSeg], (unsigned long long)acc);
                        atomicAdd(&counts[curSeg], cnt);
                    }
                }
                curSeg = s; acc = q; cnt = 1;
            } else { acc += q; ++cnt; }
        }
        if (cnt) {
            int idx = curSeg - segFirst;
            if (idx < CAP) {
                atomicAdd(&aggP[idx], (unsigned long long)acc);
                atomicAdd(&aggC[idx], cnt);
            } else {
                atomicAdd(&pooled[curSeg], (unsigned long long)acc);
                atomicAdd(&counts[curSeg], cnt);
            }
        }
    }
    __syncthreads();
    if (tid < CAP) {
        int c = aggC[tid];
        if (c) {
            atomicAdd(&pooled[segFirst + tid], aggP[tid]);
            atomicAdd(&counts[segFirst + tid], c);
        }
    }
}

// ---- k_out: one block per segment, write the constant weight run ----
__global__ __launch_bounds__(128) void k_out(
    const unsigned long long* __restrict__ pooled, const int* __restrict__ counts,
    const int* __restrict__ seg_start, const float* __restrict__ b3,
    float* __restrict__ out)
{
    const int s = blockIdx.x;
    const int cnt = counts[s];
    if (cnt == 0) return;
    const int start = seg_start[s];

    long long pv = (long long)pooled[s];
    double mean = ((double)pv / SCALE) / (double)cnt;
    float w = fmaxf((float)(mean + (double)b3[0]), 0.0f);

    const int tid = threadIdx.x;
    int a = (start + 3) & ~3;               // align to float4
    int head = min(a - start, cnt);
    if (tid < head) out[start + tid] = w;
    int rem = cnt - head;
    if (rem <= 0) return;
    int nvec = rem >> 2;
    float4 wv = make_float4(w, w, w, w);
    float4* o4 = (float4*)(out + start + head);
    for (int i = tid; i < nvec; i += 128) o4[i] = wv;
    int tail = rem & 3;
    if (tid < tail) out[start + head + (nvec << 2) + tid] = w;
}

extern "C" void kernel_launch(void* const* d_in, const int* in_sizes, int n_in,
                              void* d_out, int out_size, void* d_ws, size_t ws_size,
                              hipStream_t stream)
{
    const float* x   = (const float*)d_in[0];
    const int* batch = (const int*)d_in[1];
    const float* W1 = (const float*)d_in[2];
    const float* b1 = (const float*)d_in[3];
    const float* W2 = (const float*)d_in[4];
    const float* b2 = (const float*)d_in[5];
    const float* W3 = (const float*)d_in[6];
    const float* b3 = (const float*)d_in[7];
    float* out = (float*)d_out;
    const int n = in_sizes[0];

    char* ws = (char*)d_ws;
    unsigned long long* pooled = (unsigned long long*)ws;   // 16384  -> 16384
    int*    counts   = (int*)(ws + 16384);                  //  8192  -> 24576
    float*  bpg      = (float*)(ws + 24576);                //   256  -> 24832
    int*    nvalid   = (int*)(ws + 24832);                  //   272  -> 25104
    int*    seg_start= (int*)(ws + 25104);                  //  8192  -> 33296
    float*  knots2d  = (float*)(ws + 33296);                // 16912  -> 50208
    float2* coef2d   = (float2*)(ws + 50208);               // 33808  -> 84016
    float*  Tflat    = (float*)(ws + 84016);                // 16960  -> 100976
    float2* Cflat    = (float2*)(ws + 100976);              // 33808  -> 134784
    float4* cellTab  = (float4*)(ws + 134784);              // 65536  -> ~200 KB

    k_pre_ab<<<65, 64, 0, stream>>>(W1, b1, W2, b2, W3, pooled, counts,
                                    bpg, knots2d, coef2d, nvalid);
    k_pre_c2<<<65, 64, 0, stream>>>(bpg, nvalid, knots2d, coef2d,
                                    Tflat, Cflat, cellTab);

    const int eblocks = (int)((n + 256LL * PPT_E - 1) / (256LL * PPT_E));
    k_eval<<<eblocks, 256, 0, stream>>>(x, batch, Tflat, Cflat, cellTab,
                                        pooled, counts, seg_start, n);
    k_out<<<NSEG, 128, 0, stream>>>(pooled, counts, seg_start, b3, out);
}

// Round 11
// 34.889 us; speedup vs baseline: 1.1193x; 1.1193x over previous
//
#include <hip/hip_runtime.h>
#include <math.h>

#define NSEG 2048
#define ROW 65
#define MMAX 4226          // max flat coef entries (M+1), M <= 64*65+64 = 4224
#define TCAP 4240          // flat knot array capacity incl window-read padding
#define NC 4096            // grid cells
#define GLO (-9.0f)
#define GHI (9.0f)
#define DXF ((GHI - GLO) / NC)
#define INVDX (NC / (GHI - GLO))
#define PPT_E 4            // eval: 1954 blocks, ~30 waves/CU (latency-bound)
#define CAP 64             // per-block segment-aggregation slots
#define SCALEF 1073741824.0f  // 2^30 (exact exponent shift in fp32)
#define SCALE  1073741824.0

// ---- k_pre_ab: zero accumulators + per-interval crossing tables ----
__global__ __launch_bounds__(64) void k_pre_ab(
    const float* __restrict__ W1, const float* __restrict__ b1,
    const float* __restrict__ W2, const float* __restrict__ b2,
    const float* __restrict__ W3,
    unsigned long long* __restrict__ pooled, int* __restrict__ counts,
    float* __restrict__ bpg, float* __restrict__ knots, float2* __restrict__ coef,
    int* __restrict__ nvalid)
{
    __shared__ float bps[64];
    __shared__ float w2s[64 * 65];   // padded: row stride 65 kills bank conflicts
    __shared__ float sc_[64], sda[64], sdb[64];
    const int lane = threadIdx.x;
    const int k = blockIdx.x;

    // zero the global accumulators (spread across the 65 blocks)
    for (int i = k * 64 + lane; i < NSEG; i += 65 * 64) { pooled[i] = 0ull; counts[i] = 0; }

    // breakpoints: t_j = -b1/W1 (W1==0 -> sentinel), stable shfl rank-sort
    float w1l = W1[lane], b1l = b1[lane];
    float t = (w1l != 0.0f) ? (-b1l / w1l) : 3.0e38f;
    int r = 0;
    for (int l = 0; l < 64; ++l) {
        float o = __shfl(t, l);
        r += (o < t) || (o == t && l < lane);
    }
    bps[r] = t;

    // stage W2 into padded LDS (coalesced global reads)
    for (int i = lane; i < 4096; i += 64)
        w2s[(i >> 6) * 65 + (i & 63)] = W2[i];
    __syncthreads();
    if (k == 0) bpg[lane] = bps[lane];

    // affine coeffs of z_i (i = lane) on interval k: z = a*x + b
    float lof = (k == 0) ? (bps[0] - 1.0f) : bps[k - 1];
    float hif = (k == 64) ? (bps[63] + 1.0f) : bps[k];
    float xm = lof + 0.5f * (hif - lof);
    float a = 0.0f, b = b2[lane];
    for (int j = 0; j < 64; ++j) {
        float w1 = W1[j];
        if (w1 * xm + b1[j] > 0.0f) {
            float w2 = w2s[lane * 65 + j];
            a += w2 * w1;
            b += w2 * b1[j];
        }
    }

    // outer-relu crossing of z_i inside the open interval
    float w3 = W3[lane];
    float lo = (k == 0) ? -INFINITY : bps[k - 1];
    float hi = (k == 64) ? INFINITY : bps[k];
    float c = INFINITY, da = 0.0f, db = 0.0f;
    if (a != 0.0f) {
        float cc = -b / a;
        if (cc > lo && cc < hi) {
            float s = (a > 0.0f) ? 1.0f : -1.0f;
            c = cc; da = s * w3 * a; db = s * w3 * b;
        }
    }
    // active set just right of left edge -> (a0,b0)
    bool act;
    if (k == 0) act = (a < 0.0f) || (a == 0.0f && b > 0.0f);
    else { float v = a * lo + b; act = (v > 0.0f) || (v == 0.0f && a > 0.0f); }
    float a0 = act ? w3 * a : 0.0f;
    float b0 = act ? w3 * b : 0.0f;
    for (int d = 32; d; d >>= 1) { a0 += __shfl_xor(a0, d); b0 += __shfl_xor(b0, d); }

    // stable rank sort of crossings (inf = invalid go last); scatter via LDS
    int rank = 0;
    for (int l = 0; l < 64; ++l) {
        float o = __shfl(c, l);
        rank += (o < c) || (o == c && l < lane);
    }
    sc_[rank] = c; sda[rank] = da; sdb[rank] = db;
    __syncthreads();
    float cs = sc_[lane], das = sda[lane], dbs = sdb[lane];
    for (int d = 1; d < 64; d <<= 1) {  // inclusive scan in sorted order
        float ta = __shfl_up(das, d);
        float tb = __shfl_up(dbs, d);
        if (lane >= d) { das += ta; dbs += tb; }
    }
    knots[k * ROW + lane] = cs;
    if (lane == 0) coef[k * ROW] = make_float2(a0, b0);
    coef[k * ROW + lane + 1] = make_float2(a0 + das, b0 + dbs);

    unsigned long long vm = __ballot(isfinite(cs));
    if (lane == 0) nvalid[k] = (int)__popcll(vm);
}

// ---- k_pre_c2: parallel flatten + grid fill (65 blocks x 64 threads) ----
__global__ __launch_bounds__(64) void k_pre_c2(
    const float* __restrict__ bpg, const int* __restrict__ nvalid,
    const float* __restrict__ knots2d, const float2* __restrict__ coef2d,
    float* __restrict__ Tf, float2* __restrict__ Cf,
    unsigned short* __restrict__ baseg, int* __restrict__ Mg)
{
    const int lane = threadIdx.x;
    const int k = blockIdx.x;
    __shared__ float bps[64];
    __shared__ float trow[64];

    bps[lane] = bpg[lane];
    trow[lane] = knots2d[k * ROW + lane];   // sorted fine knots, inf past nvalid

    // off[k] = sum_{k'<k} (nvalid[k']+1) via inclusive shfl scan over 64 lanes
    int v = nvalid[lane] + 1;
    int sc = v;
    for (int d = 1; d < 64; d <<= 1) {
        int tt = __shfl_up(sc, d);
        if (lane >= d) sc += tt;
    }
    const int offk  = (k == 0) ? 0 : __shfl(sc, k - 1);
    const int off64 = __shfl(sc, 63);
    const int nv    = nvalid[k];
    __syncthreads();

    // flat row slice: nv fine knots, then coarse bps[k] (k<64); coef j=0..nv
    for (int j = lane; j <= nv; j += 64) {
        if (j < nv) Tf[offk + j] = trow[j];
        else if (k < 64) Tf[offk + j] = bps[k];
        Cf[offk + j] = coef2d[k * ROW + j];
    }
    if (k == 64) {  // sentinels + coef pad beyond M; publish M
        const int M = off64 + nvalid[64];
        float2 lastC = coef2d[64 * ROW + nvalid[64]];
        for (int i = M + lane; i < TCAP; i += 64) Tf[i] = INFINITY;
        for (int i = M + 1 + lane; i < MMAX; i += 64) Cf[i] = lastC;
        if (lane == 0) Mg[0] = M;
    }

    // grid cells owned by interval k: left in [bps[k-1], bps[k])
    float lob = (k == 0) ? GLO : bps[k - 1];
    float hib = (k == 64) ? GHI : bps[k];
    float clo = fminf(fmaxf((lob - GLO) * INVDX, 0.0f), (float)(NC - 1));
    float chi = fminf(fmaxf((hib - GLO) * INVDX, 0.0f), (float)(NC - 1));
    int c0 = max(0, (int)clo - 1);
    int c1 = min(NC - 1, (int)chi + 1);
    for (int c = c0 + lane; c <= c1; c += 64) {
        float left = GLO + c * DXF;
        bool ok = (k == 0 || left >= bps[k - 1]) && (k == 64 || left < bps[k]);
        if (ok) {
            int j = 0;  // #{fine knots <= left}; inf-padding makes 64-search safe
#pragma unroll
            for (int ofs = 32; ofs >= 1; ofs >>= 1)
                if (trow[j + ofs - 1] <= left) j += ofs;
            if (j < 64 && trow[j] <= left) ++j;
            baseg[c] = (unsigned short)(offk + j);
        }
    }
}

// ---- k_eval: 3-phase (index / coef / accumulate) for cross-point ILP ----
__global__ __launch_bounds__(256) void k_eval(
    const float* __restrict__ x, const int* __restrict__ batch,
    const float* __restrict__ Tf, const float2* __restrict__ Cf,
    const unsigned short* __restrict__ baseg, const int* __restrict__ Mg,
    unsigned long long* __restrict__ pooled, int* __restrict__ counts,
    int* __restrict__ seg_start, int n)
{
    __shared__ __align__(16) float T_s[TCAP];
    __shared__ unsigned long long aggP[CAP];
    __shared__ int aggC[CAP];
    __shared__ int segFirst_s;
    __shared__ int lastSeg_s[256];
    const int tid = threadIdx.x;

    // stage only the live part of the knot table
    const int stageN = min(TCAP, (Mg[0] + 32) & ~15);
    for (int i = tid; i < (stageN >> 2); i += 256)
        ((float4*)T_s)[i] = ((const float4*)Tf)[i];
    if (tid < CAP) { aggP[tid] = 0ull; aggC[tid] = 0; }

    long long base = ((long long)blockIdx.x * 256 + tid) * PPT_E;
    const bool active = base < n;   // n % PPT_E == 0 -> active threads do full vectors

    float xs[PPT_E]; int ss[PPT_E];
    if (active) {
        float4 xv4 = *(const float4*)(x + base);
        int4   s4  = *(const int4*)(batch + base);
        xs[0] = xv4.x; xs[1] = xv4.y; xs[2] = xv4.z; xs[3] = xv4.w;
        ss[0] = s4.x;  ss[1] = s4.y;  ss[2] = s4.z;  ss[3] = s4.w;
        if (tid == 0) segFirst_s = ss[0];
        lastSeg_s[tid] = ss[PPT_E - 1];
    }
    __syncthreads();
    const int segFirst = segFirst_s;

    if (active) {
        // segment-boundary detection: neighbor handoff via LDS (active threads
        // are a prefix, so tid-1 is active whenever tid is); 1 global load/block
        int prev = (tid == 0) ? ((base > 0) ? batch[base - 1] : -1)
                              : lastSeg_s[tid - 1];
        if (ss[0] != prev) seg_start[ss[0]] = (int)base;
#pragma unroll
        for (int p = 1; p < PPT_E; ++p)
            if (ss[p] != ss[p - 1]) seg_start[ss[p]] = (int)(base + p);

        // phase A: per-point flat index (4 chains issue together)
        int mm[PPT_E];
#pragma unroll
        for (int p = 0; p < PPT_E; ++p) {
            float xv = xs[p];
            int m;
            if (xv >= GLO) {
                int c = (int)((xv - GLO) * INVDX);
                c = c < NC - 1 ? c : NC - 1;
                if (c > 0 && GLO + c * DXF > xv) --c;  // fp rounding guard
                int b0i = baseg[c];
                int a0 = b0i & ~3;
                // 12-entry LDS window from a0: entries below b0i are <= x by
                // grid construction, so m = a0 + count(T[a0..a0+11] <= x).
                const float4* tw = (const float4*)(T_s + a0);
                float4 t0 = tw[0], t1 = tw[1], t2 = tw[2];
                int cw = (t0.x <= xv) + (t0.y <= xv) + (t0.z <= xv) + (t0.w <= xv)
                       + (t1.x <= xv) + (t1.y <= xv) + (t1.z <= xv) + (t1.w <= xv)
                       + (t2.x <= xv) + (t2.y <= xv) + (t2.z <= xv) + (t2.w <= xv);
                m = a0 + cw;
                if (cw == 12) { while (T_s[m] <= xv) ++m; }  // ~never taken
            } else m = 0;
            mm[p] = m;
        }

        // phase B: coefficient loads + quantize (4 Cf loads in flight)
        long long qv[PPT_E];
#pragma unroll
        for (int p = 0; p < PPT_E; ++p) {
            float2 ab = Cf[mm[p]];
            qv[p] = (long long)(fmaf(ab.x, xs[p], ab.y) * SCALEF);  // exact 2^30 shift
        }

        // phase C: branchy segment accumulate on registers only
        int curSeg = -1; long long acc = 0; int cnt = 0;
#pragma unroll
        for (int p = 0; p < PPT_E; ++p) {
            int s = ss[p];
            if (s != curSeg) {
                if (cnt) {
                    int idx = curSeg - segFirst;
                    if (idx < CAP) {
                        atomicAdd(&aggP[idx], (unsigned long long)acc);
                        atomicAdd(&aggC[idx], cnt);
                    } else {
                        atomicAdd(&pooled[curSeg], (unsigned long long)acc);
                        atomicAdd(&counts[curSeg], cnt);
                    }
                }
                curSeg = s; acc = qv[p]; cnt = 1;
            } else { acc += qv[p]; ++cnt; }
        }
        if (cnt) {
            int idx = curSeg - segFirst;
            if (idx < CAP) {
                atomicAdd(&aggP[idx], (unsigned long long)acc);
                atomicAdd(&aggC[idx], cnt);
            } else {
                atomicAdd(&pooled[curSeg], (unsigned long long)acc);
                atomicAdd(&counts[curSeg], cnt);
            }
        }
    }
    __syncthreads();
    if (tid < CAP) {
        int c = aggC[tid];
        if (c) {
            atomicAdd(&pooled[segFirst + tid], aggP[tid]);
            atomicAdd(&counts[segFirst + tid], c);
        }
    }
}

// ---- k_out: one block per segment, write the constant weight run ----
__global__ __launch_bounds__(128) void k_out(
    const unsigned long long* __restrict__ pooled, const int* __restrict__ counts,
    const int* __restrict__ seg_start, const float* __restrict__ b3,
    float* __restrict__ out)
{
    const int s = blockIdx.x;
    const int cnt = counts[s];
    if (cnt == 0) return;
    const int start = seg_start[s];

    long long pv = (long long)pooled[s];
    double mean = ((double)pv / SCALE) / (double)cnt;
    float w = fmaxf((float)(mean + (double)b3[0]), 0.0f);

    const int tid = threadIdx.x;
    int a = (start + 3) & ~3;               // align to float4
    int head = min(a - start, cnt);
    if (tid < head) out[start + tid] = w;
    int rem = cnt - head;
    if (rem <= 0) return;
    int nvec = rem >> 2;
    float4 wv = make_float4(w, w, w, w);
    float4* o4 = (float4*)(out + start + head);
    for (int i = tid; i < nvec; i += 128) o4[i] = wv;
    int tail = rem & 3;
    if (tid < tail) out[start + head + (nvec << 2) + tid] = w;
}

extern "C" void kernel_launch(void* const* d_in, const int* in_sizes, int n_in,
                              void* d_out, int out_size, void* d_ws, size_t ws_size,
                              hipStream_t stream)
{
    const float* x   = (const float*)d_in[0];
    const int* batch = (const int*)d_in[1];
    const float* W1 = (const float*)d_in[2];
    const float* b1 = (const float*)d_in[3];
    const float* W2 = (const float*)d_in[4];
    const float* b2 = (const float*)d_in[5];
    const float* W3 = (const float*)d_in[6];
    const float* b3 = (const float*)d_in[7];
    float* out = (float*)d_out;
    const int n = in_sizes[0];

    char* ws = (char*)d_ws;
    unsigned long long* pooled = (unsigned long long*)ws;   // 16384  -> 16384
    int*    counts   = (int*)(ws + 16384);                  //  8192  -> 24576
    float*  bpg      = (float*)(ws + 24576);                //   256  -> 24832
    int*    nvalid   = (int*)(ws + 24832);                  //   272  -> 25104
    int*    Mg       = (int*)(ws + 25104);                  //    16  -> 25120
    int*    seg_start= (int*)(ws + 25120);                  //  8192  -> 33312
    float*  knots2d  = (float*)(ws + 33312);                // 16912  -> 50224
    float2* coef2d   = (float2*)(ws + 50224);               // 33808  -> 84032
    float*  Tflat    = (float*)(ws + 84032);                // 16960  -> 100992
    float2* Cflat    = (float2*)(ws + 100992);              // 33808  -> 134800
    unsigned short* baseg = (unsigned short*)(ws + 134800); //  8192  -> ~143 KB

    k_pre_ab<<<65, 64, 0, stream>>>(W1, b1, W2, b2, W3, pooled, counts,
                                    bpg, knots2d, coef2d, nvalid);
    k_pre_c2<<<65, 64, 0, stream>>>(bpg, nvalid, knots2d, coef2d,
                                    Tflat, Cflat, baseg, Mg);

    const int eblocks = (int)((n + 256LL * PPT_E - 1) / (256LL * PPT_E));
    k_eval<<<eblocks, 256, 0, stream>>>(x, batch, Tflat, Cflat, baseg, Mg,
                                        pooled, counts, seg_start, n);
    k_out<<<NSEG, 128, 0, stream>>>(pooled, counts, seg_start, b3, out);
}

// Round 12
// 30.017 us; speedup vs baseline: 1.3010x; 1.1623x over previous
//
#include <hip/hip_runtime.h>
#include <math.h>

#define NSEG 2048
#define ROW 65
#define MMAX 4226          // max flat coef entries (M+1), M <= 64*65+64 = 4224
#define TCAP 4240          // flat knot array capacity incl window-read padding
#define NC 4096            // grid cells
#define GLO (-9.0f)
#define GHI (9.0f)
#define DXF ((GHI - GLO) / NC)
#define INVDX (NC / (GHI - GLO))
#define SCAN_PPT 8         // points per scan thread in K1

// ---- K1: pre_ab (blocks 0..64) + segment-boundary scan (blocks 65..) ----
__global__ __launch_bounds__(256) void k_pre_scan(
    const float* __restrict__ W1, const float* __restrict__ b1,
    const float* __restrict__ W2, const float* __restrict__ b2,
    const float* __restrict__ W3, const int* __restrict__ batch,
    float* __restrict__ bpg, float* __restrict__ knots, float2* __restrict__ coef,
    int* __restrict__ nvalid, int* __restrict__ seg_start, int* __restrict__ seg_end,
    int n)
{
    __shared__ float bps[64];
    __shared__ float w2s[64 * 65];   // padded: row stride 65 kills bank conflicts
    __shared__ float sc_[64], sda[64], sdb[64];
    const int tid = threadIdx.x;

    if (blockIdx.x >= 65) {
        // ---- segment scan: dense seg_start/seg_end over sorted batch ----
        int bid2 = blockIdx.x - 65;
        int base = bid2 * (256 * SCAN_PPT) + tid * SCAN_PPT;
        if (base >= n) return;
        const int4* bp = (const int4*)(batch + base);
        int4 a4 = bp[0], b4 = bp[1];
        int ss[SCAN_PPT] = {a4.x, a4.y, a4.z, a4.w, b4.x, b4.y, b4.z, b4.w};
        int prev = (base > 0) ? batch[base - 1] : -1;
#pragma unroll
        for (int p = 0; p < SCAN_PPT; ++p) {
            int u = (p == 0) ? prev : ss[p - 1];
            int v = ss[p];
            if (v != u) {
                int i = base + p;
                for (int s = (u > 0 ? u : 0); s < v; ++s) seg_end[s] = i;
                for (int s = u + 1; s <= v; ++s) seg_start[s] = i;
            }
        }
        if (base + SCAN_PPT >= n) {   // true last thread (n % SCAN_PPT == 0)
            int u = ss[SCAN_PPT - 1];
            for (int s = u; s < NSEG; ++s) seg_end[s] = n;
            for (int s = u + 1; s < NSEG; ++s) seg_start[s] = n;
        }
        return;
    }

    // ---- pre_ab: per-interval crossing tables (wave 0 does the wave math) ----
    const int k = blockIdx.x;
    const int lane = tid & 63;

    if (tid < 64) {
        // breakpoints: t = -b1/W1 (W1==0 -> sentinel), stable shfl rank-sort
        float w1l = W1[lane], b1l = b1[lane];
        float t = (w1l != 0.0f) ? (-b1l / w1l) : 3.0e38f;
        int r = 0;
        for (int l = 0; l < 64; ++l) {
            float o = __shfl(t, l);
            r += (o < t) || (o == t && l < lane);
        }
        bps[r] = t;
    }
    for (int i = tid; i < 4096; i += 256)
        w2s[(i >> 6) * 65 + (i & 63)] = W2[i];
    __syncthreads();
    if (k == 0 && tid < 64) bpg[lane] = bps[lane];

    float a0 = 0.0f, b0 = 0.0f;
    if (tid < 64) {
        // affine coeffs of z_i (i = lane) on interval k: z = a*x + b
        float lof = (k == 0) ? (bps[0] - 1.0f) : bps[k - 1];
        float hif = (k == 64) ? (bps[63] + 1.0f) : bps[k];
        float xm = lof + 0.5f * (hif - lof);
        float a = 0.0f, b = b2[lane];
        for (int j = 0; j < 64; ++j) {
            float w1 = W1[j];
            if (w1 * xm + b1[j] > 0.0f) {
                float w2 = w2s[lane * 65 + j];
                a += w2 * w1;
                b += w2 * b1[j];
            }
        }

        float w3 = W3[lane];
        float lo = (k == 0) ? -INFINITY : bps[k - 1];
        float hi = (k == 64) ? INFINITY : bps[k];
        float c = INFINITY, da = 0.0f, db = 0.0f;
        if (a != 0.0f) {
            float cc = -b / a;
            if (cc > lo && cc < hi) {
                float s = (a > 0.0f) ? 1.0f : -1.0f;
                c = cc; da = s * w3 * a; db = s * w3 * b;
            }
        }
        bool act;
        if (k == 0) act = (a < 0.0f) || (a == 0.0f && b > 0.0f);
        else { float v = a * lo + b; act = (v > 0.0f) || (v == 0.0f && a > 0.0f); }
        a0 = act ? w3 * a : 0.0f;
        b0 = act ? w3 * b : 0.0f;
        for (int d = 32; d; d >>= 1) { a0 += __shfl_xor(a0, d); b0 += __shfl_xor(b0, d); }

        int rank = 0;
        for (int l = 0; l < 64; ++l) {
            float o = __shfl(c, l);
            rank += (o < c) || (o == c && l < lane);
        }
        sc_[rank] = c; sda[rank] = da; sdb[rank] = db;
    }
    __syncthreads();
    if (tid < 64) {
        float cs = sc_[lane], das = sda[lane], dbs = sdb[lane];
        for (int d = 1; d < 64; d <<= 1) {  // inclusive scan in sorted order
            float ta = __shfl_up(das, d);
            float tb = __shfl_up(dbs, d);
            if (lane >= d) { das += ta; dbs += tb; }
        }
        knots[k * ROW + lane] = cs;
        if (lane == 0) coef[k * ROW] = make_float2(a0, b0);
        coef[k * ROW + lane + 1] = make_float2(a0 + das, b0 + dbs);

        unsigned long long vm = __ballot(isfinite(cs));
        if (lane == 0) nvalid[k] = (int)__popcll(vm);
    }
}

// ---- K2: parallel flatten + grid fill (65 blocks x 64 threads) ----
__global__ __launch_bounds__(64) void k_pre_c2(
    const float* __restrict__ bpg, const int* __restrict__ nvalid,
    const float* __restrict__ knots2d, const float2* __restrict__ coef2d,
    float* __restrict__ Tf, float2* __restrict__ Cf,
    unsigned short* __restrict__ baseg, int* __restrict__ Mg)
{
    const int lane = threadIdx.x;
    const int k = blockIdx.x;
    __shared__ float bps[64];
    __shared__ float trow[64];

    bps[lane] = bpg[lane];
    trow[lane] = knots2d[k * ROW + lane];   // sorted fine knots, inf past nvalid

    // off[k] = sum_{k'<k} (nvalid[k']+1) via inclusive shfl scan over 64 lanes
    int v = nvalid[lane] + 1;
    int sc = v;
    for (int d = 1; d < 64; d <<= 1) {
        int tt = __shfl_up(sc, d);
        if (lane >= d) sc += tt;
    }
    const int offk  = (k == 0) ? 0 : __shfl(sc, k - 1);
    const int off64 = __shfl(sc, 63);
    const int nv    = nvalid[k];
    __syncthreads();

    // flat row slice: nv fine knots, then coarse bps[k] (k<64); coef j=0..nv
    for (int j = lane; j <= nv; j += 64) {
        if (j < nv) Tf[offk + j] = trow[j];
        else if (k < 64) Tf[offk + j] = bps[k];
        Cf[offk + j] = coef2d[k * ROW + j];
    }
    if (k == 64) {  // sentinels + coef pad beyond M; publish M
        const int M = off64 + nvalid[64];
        float2 lastC = coef2d[64 * ROW + nvalid[64]];
        for (int i = M + lane; i < TCAP; i += 64) Tf[i] = INFINITY;
        for (int i = M + 1 + lane; i < MMAX; i += 64) Cf[i] = lastC;
        if (lane == 0) Mg[0] = M;
    }

    // grid cells owned by interval k: left in [bps[k-1], bps[k])
    float lob = (k == 0) ? GLO : bps[k - 1];
    float hib = (k == 64) ? GHI : bps[k];
    float clo = fminf(fmaxf((lob - GLO) * INVDX, 0.0f), (float)(NC - 1));
    float chi = fminf(fmaxf((hib - GLO) * INVDX, 0.0f), (float)(NC - 1));
    int c0 = max(0, (int)clo - 1);
    int c1 = min(NC - 1, (int)chi + 1);
    for (int c = c0 + lane; c <= c1; c += 64) {
        float left = GLO + c * DXF;
        bool ok = (k == 0 || left >= bps[k - 1]) && (k == 64 || left < bps[k]);
        if (ok) {
            int j = 0;  // #{fine knots <= left}; inf-padding makes 64-search safe
#pragma unroll
            for (int ofs = 32; ofs >= 1; ofs >>= 1)
                if (trow[j + ofs - 1] <= left) j += ofs;
            if (j < 64 && trow[j] <= left) ++j;
            baseg[c] = (unsigned short)(offk + j);
        }
    }
}

// ---- K3: one block per segment -> eval g(x) over the run, reduce, broadcast ----
__global__ __launch_bounds__(256) void k_eval_out(
    const float* __restrict__ x,
    const int* __restrict__ seg_start, const int* __restrict__ seg_end,
    const float* __restrict__ Tf, const float2* __restrict__ Cf,
    const unsigned short* __restrict__ baseg, const int* __restrict__ Mg,
    const float* __restrict__ b3, float* __restrict__ out)
{
    __shared__ __align__(16) float T_s[TCAP];
    __shared__ double wsum[4];
    __shared__ float w_s;
    const int tid = threadIdx.x;
    const int s = blockIdx.x;

    // stage only the live part of the knot table (~a few KB)
    const int stageN = min(TCAP, (Mg[0] + 32) & ~15);
    for (int i = tid; i < (stageN >> 2); i += 256)
        ((float4*)T_s)[i] = ((const float4*)Tf)[i];

    const int start = seg_start[s];
    const int end   = seg_end[s];
    __syncthreads();
    if (start >= end) return;          // empty segment: nothing to write

    // eval + per-thread f64 accumulate over the segment's contiguous run
    double acc = 0.0;
    for (int i = start + tid; i < end; i += 256) {
        float xv = x[i];
        int m;
        if (xv >= GLO) {
            int c = (int)((xv - GLO) * INVDX);
            c = c < NC - 1 ? c : NC - 1;
            if (c > 0 && GLO + c * DXF > xv) --c;  // fp rounding guard
            int b0i = baseg[c];
            int a0 = b0i & ~3;
            // 12-entry LDS window from a0: entries below b0i are <= x by grid
            // construction, so m = a0 + count(T[a0..a0+11] <= x).
            const float4* tw = (const float4*)(T_s + a0);
            float4 t0 = tw[0], t1 = tw[1], t2 = tw[2];
            int cw = (t0.x <= xv) + (t0.y <= xv) + (t0.z <= xv) + (t0.w <= xv)
                   + (t1.x <= xv) + (t1.y <= xv) + (t1.z <= xv) + (t1.w <= xv)
                   + (t2.x <= xv) + (t2.y <= xv) + (t2.z <= xv) + (t2.w <= xv);
            m = a0 + cw;
            if (cw == 12) { while (T_s[m] <= xv) ++m; }  // ~never taken
        } else m = 0;
        float2 ab = Cf[m];
        acc += (double)fmaf(ab.x, xv, ab.y);
    }

    // deterministic tree reduction: wave shfl + 4 partials in LDS
    for (int d = 32; d; d >>= 1) acc += __shfl_down(acc, d);
    if ((tid & 63) == 0) wsum[tid >> 6] = acc;
    __syncthreads();
    if (tid == 0) {
        double tot = wsum[0] + wsum[1] + wsum[2] + wsum[3];
        double mean = tot / (double)(end - start);
        w_s = fmaxf((float)(mean + (double)b3[0]), 0.0f);
    }
    __syncthreads();
    const float w = w_s;
    for (int i = start + tid; i < end; i += 256) out[i] = w;
}

extern "C" void kernel_launch(void* const* d_in, const int* in_sizes, int n_in,
                              void* d_out, int out_size, void* d_ws, size_t ws_size,
                              hipStream_t stream)
{
    const float* x   = (const float*)d_in[0];
    const int* batch = (const int*)d_in[1];
    const float* W1 = (const float*)d_in[2];
    const float* b1 = (const float*)d_in[3];
    const float* W2 = (const float*)d_in[4];
    const float* b2 = (const float*)d_in[5];
    const float* W3 = (const float*)d_in[6];
    const float* b3 = (const float*)d_in[7];
    float* out = (float*)d_out;
    const int n = in_sizes[0];

    char* ws = (char*)d_ws;
    int*    seg_start= (int*)ws;                            //  8192  -> 8192
    int*    seg_end  = (int*)(ws + 8192);                   //  8192  -> 16384
    float*  bpg      = (float*)(ws + 16384);                //   256  -> 16640
    int*    nvalid   = (int*)(ws + 16640);                  //   272  -> 16912
    int*    Mg       = (int*)(ws + 16912);                  //    16  -> 16928
    float*  knots2d  = (float*)(ws + 16928);                // 16912  -> 33840
    float2* coef2d   = (float2*)(ws + 33840);               // 33808  -> 67648
    float*  Tflat    = (float*)(ws + 67648);                // 16960  -> 84608
    float2* Cflat    = (float2*)(ws + 84608);               // 33808  -> 118416
    unsigned short* baseg = (unsigned short*)(ws + 118416); //  8192  -> ~127 KB

    const int scanBlocks = (n + 256 * SCAN_PPT - 1) / (256 * SCAN_PPT);
    k_pre_scan<<<65 + scanBlocks, 256, 0, stream>>>(
        W1, b1, W2, b2, W3, batch, bpg, knots2d, coef2d, nvalid,
        seg_start, seg_end, n);
    k_pre_c2<<<65, 64, 0, stream>>>(bpg, nvalid, knots2d, coef2d,
                                    Tflat, Cflat, baseg, Mg);
    k_eval_out<<<NSEG, 256, 0, stream>>>(x, seg_start, seg_end, Tflat, Cflat,
                                         baseg, Mg, b3, out);
}

// Round 13
// 27.041 us; speedup vs baseline: 1.4442x; 1.1101x over previous
//
#include <hip/hip_runtime.h>
#include <math.h>

#define NSEG 2048
#define ROW 65
#define N2D (65 * ROW)     // 2D knot/coef table size (4225)
#define SCAN_PPT 8         // points per scan thread in K1

// ---- K1: pre_ab (blocks 0..64) + segment-boundary scan (blocks 65..) ----
__global__ __launch_bounds__(256) void k_pre_scan(
    const float* __restrict__ W1, const float* __restrict__ b1,
    const float* __restrict__ W2, const float* __restrict__ b2,
    const float* __restrict__ W3, const int* __restrict__ batch,
    float* __restrict__ bpg, float* __restrict__ knots, float2* __restrict__ coef,
    int* __restrict__ seg_start, int* __restrict__ seg_end, int n)
{
    __shared__ float bps[64];
    __shared__ float w2s[64 * 65];   // padded: row stride 65 kills bank conflicts
    __shared__ float sc_[64], sda[64], sdb[64];
    const int tid = threadIdx.x;

    if (blockIdx.x >= 65) {
        // ---- segment scan: dense seg_start/seg_end over sorted batch ----
        int bid2 = blockIdx.x - 65;
        int base = bid2 * (256 * SCAN_PPT) + tid * SCAN_PPT;
        if (base >= n) return;
        const int4* bp = (const int4*)(batch + base);
        int4 a4 = bp[0], b4 = bp[1];
        int ss[SCAN_PPT] = {a4.x, a4.y, a4.z, a4.w, b4.x, b4.y, b4.z, b4.w};
        int prev = (base > 0) ? batch[base - 1] : -1;
#pragma unroll
        for (int p = 0; p < SCAN_PPT; ++p) {
            int u = (p == 0) ? prev : ss[p - 1];
            int v = ss[p];
            if (v != u) {
                int i = base + p;
                for (int s = (u > 0 ? u : 0); s < v; ++s) seg_end[s] = i;
                for (int s = u + 1; s <= v; ++s) seg_start[s] = i;
            }
        }
        if (base + SCAN_PPT >= n) {   // true last thread (n % SCAN_PPT == 0)
            int u = ss[SCAN_PPT - 1];
            for (int s = u; s < NSEG; ++s) seg_end[s] = n;
            for (int s = u + 1; s < NSEG; ++s) seg_start[s] = n;
        }
        return;
    }

    // ---- pre_ab: per-interval crossing tables (wave 0 does the wave math) ----
    const int k = blockIdx.x;
    const int lane = tid & 63;

    if (tid < 64) {
        // breakpoints: t = -b1/W1 (W1==0 -> sentinel), stable shfl rank-sort
        float w1l = W1[lane], b1l = b1[lane];
        float t = (w1l != 0.0f) ? (-b1l / w1l) : 3.0e38f;
        int r = 0;
        for (int l = 0; l < 64; ++l) {
            float o = __shfl(t, l);
            r += (o < t) || (o == t && l < lane);
        }
        bps[r] = t;
    }
    for (int i = tid; i < 4096; i += 256)
        w2s[(i >> 6) * 65 + (i & 63)] = W2[i];
    __syncthreads();
    if (k == 0 && tid < 64) bpg[lane] = bps[lane];

    float a0 = 0.0f, b0 = 0.0f;
    if (tid < 64) {
        // affine coeffs of z_i (i = lane) on interval k: z = a*x + b
        float lof = (k == 0) ? (bps[0] - 1.0f) : bps[k - 1];
        float hif = (k == 64) ? (bps[63] + 1.0f) : bps[k];
        float xm = lof + 0.5f * (hif - lof);
        float a = 0.0f, b = b2[lane];
        for (int j = 0; j < 64; ++j) {
            float w1 = W1[j];
            if (w1 * xm + b1[j] > 0.0f) {
                float w2 = w2s[lane * 65 + j];
                a += w2 * w1;
                b += w2 * b1[j];
            }
        }

        float w3 = W3[lane];
        float lo = (k == 0) ? -INFINITY : bps[k - 1];
        float hi = (k == 64) ? INFINITY : bps[k];
        float c = INFINITY, da = 0.0f, db = 0.0f;
        if (a != 0.0f) {
            float cc = -b / a;
            if (cc > lo && cc < hi) {
                float s = (a > 0.0f) ? 1.0f : -1.0f;
                c = cc; da = s * w3 * a; db = s * w3 * b;
            }
        }
        bool act;
        if (k == 0) act = (a < 0.0f) || (a == 0.0f && b > 0.0f);
        else { float v = a * lo + b; act = (v > 0.0f) || (v == 0.0f && a > 0.0f); }
        a0 = act ? w3 * a : 0.0f;
        b0 = act ? w3 * b : 0.0f;
        for (int d = 32; d; d >>= 1) { a0 += __shfl_xor(a0, d); b0 += __shfl_xor(b0, d); }

        int rank = 0;
        for (int l = 0; l < 64; ++l) {
            float o = __shfl(c, l);
            rank += (o < c) || (o == c && l < lane);
        }
        sc_[rank] = c; sda[rank] = da; sdb[rank] = db;
    }
    __syncthreads();
    if (tid < 64) {
        float cs = sc_[lane], das = sda[lane], dbs = sdb[lane];
        for (int d = 1; d < 64; d <<= 1) {  // inclusive scan in sorted order
            float ta = __shfl_up(das, d);
            float tb = __shfl_up(dbs, d);
            if (lane >= d) { das += ta; dbs += tb; }
        }
        knots[k * ROW + lane] = cs;          // inf for invalid -> fine-search safe
        if (lane == 0) coef[k * ROW] = make_float2(a0, b0);
        coef[k * ROW + lane + 1] = make_float2(a0 + das, b0 + dbs);
    }
}

// ---- K2: one block per segment -> two-level search eval, reduce, broadcast ----
// Uses the 2D tables directly (R3-verified logic): coarse k = #{bps <= x},
// fine j = #{knots2d[k][*] <= x} (inf padding), coef = coef2d[k*65 + j].
__global__ __launch_bounds__(256) void k_eval_out(
    const float* __restrict__ x,
    const int* __restrict__ seg_start, const int* __restrict__ seg_end,
    const float* __restrict__ bpg, const float* __restrict__ knots2d,
    const float2* __restrict__ coef2d,
    const float* __restrict__ b3, float* __restrict__ out)
{
    __shared__ float bps_s[64];
    __shared__ float T2_s[N2D];
    __shared__ double wsum[4];
    __shared__ float w_s;
    const int tid = threadIdx.x;
    const int s = blockIdx.x;

    const int start = seg_start[s];
    const int end   = seg_end[s];

    // stage breakpoint vector + 2D knot table (16.9 KB, L2 broadcast)
    if (tid < 64) bps_s[tid] = bpg[tid];
    for (int i = tid; i < N2D; i += 256) T2_s[i] = knots2d[i];
    __syncthreads();
    if (start >= end) return;          // empty segment: nothing to write

    // eval + per-thread f64 accumulate over the segment's contiguous run
    double acc = 0.0;
    for (int i = start + tid; i < end; i += 256) {
        float xv = x[i];
        int k = 0;                     // coarse: k = #{bps <= xv} in [0,64]
#pragma unroll
        for (int ofs = 32; ofs >= 1; ofs >>= 1)
            if (bps_s[k + ofs - 1] <= xv) k += ofs;
        k += (k < 64 && bps_s[k] <= xv) ? 1 : 0;
        const int kb = k * ROW;
        int j = 0;                     // fine: j = #{row-k knots <= xv} in [0,64]
#pragma unroll
        for (int ofs = 32; ofs >= 1; ofs >>= 1)
            if (T2_s[kb + j + ofs - 1] <= xv) j += ofs;
        j += (j < 64 && T2_s[kb + j] <= xv) ? 1 : 0;
        float2 ab = coef2d[kb + j];    // 33.8 KB table, L1/L2 resident
        acc += (double)fmaf(ab.x, xv, ab.y);
    }

    // deterministic tree reduction: wave shfl + 4 partials in LDS
    for (int d = 32; d; d >>= 1) acc += __shfl_down(acc, d);
    if ((tid & 63) == 0) wsum[tid >> 6] = acc;
    __syncthreads();
    if (tid == 0) {
        double tot = wsum[0] + wsum[1] + wsum[2] + wsum[3];
        double mean = tot / (double)(end - start);
        w_s = fmaxf((float)(mean + (double)b3[0]), 0.0f);
    }
    __syncthreads();
    const float w = w_s;
    for (int i = start + tid; i < end; i += 256) out[i] = w;
}

extern "C" void kernel_launch(void* const* d_in, const int* in_sizes, int n_in,
                              void* d_out, int out_size, void* d_ws, size_t ws_size,
                              hipStream_t stream)
{
    const float* x   = (const float*)d_in[0];
    const int* batch = (const int*)d_in[1];
    const float* W1 = (const float*)d_in[2];
    const float* b1 = (const float*)d_in[3];
    const float* W2 = (const float*)d_in[4];
    const float* b2 = (const float*)d_in[5];
    const float* W3 = (const float*)d_in[6];
    const float* b3 = (const float*)d_in[7];
    float* out = (float*)d_out;
    const int n = in_sizes[0];

    char* ws = (char*)d_ws;
    int*    seg_start= (int*)ws;                            //  8192  -> 8192
    int*    seg_end  = (int*)(ws + 8192);                   //  8192  -> 16384
    float*  bpg      = (float*)(ws + 16384);                //   256  -> 16640
    float*  knots2d  = (float*)(ws + 16640);                // 16912  -> 33552
    float2* coef2d   = (float2*)(ws + 33552);               // 33808  -> 67360

    const int scanBlocks = (n + 256 * SCAN_PPT - 1) / (256 * SCAN_PPT);
    k_pre_scan<<<65 + scanBlocks, 256, 0, stream>>>(
        W1, b1, W2, b2, W3, batch, bpg, knots2d, coef2d,
        seg_start, seg_end, n);
    k_eval_out<<<NSEG, 256, 0, stream>>>(x, seg_start, seg_end, bpg,
                                         knots2d, coef2d, b3, out);
}